// Round 11
// baseline (173.101 us; speedup 1.0000x reference)
//
#include <hip/hip_runtime.h>
#include <stdint.h>

typedef unsigned short u16;
typedef __bf16 bf16x8 __attribute__((ext_vector_type(8)));
typedef unsigned short u16x8 __attribute__((ext_vector_type(8)));
typedef float f32x4 __attribute__((ext_vector_type(4)));
typedef uint32_t u32v4 __attribute__((ext_vector_type(4)));

#define LOG2E 1.4426950408889634f

typedef const __attribute__((address_space(1))) uint32_t as1_u32;
typedef __attribute__((address_space(3))) uint32_t as3_u32;

// float -> bf16 round-to-nearest-even
__device__ __forceinline__ u16 f2bf(float f) {
  union { float f; uint32_t i; } v; v.f = f;
  uint32_t r = (v.i + 0x7fffu + ((v.i >> 16) & 1u)) >> 16;
  return (u16)r;
}
__device__ __forceinline__ float bf2f(u16 u) {
  union { uint32_t i; float f; } v; v.i = ((uint32_t)u) << 16; return v.f;
}

// async global->LDS, 16B/lane. LDS dest = wave-uniform base; HW scatters
// lane i to base + i*16B.
__device__ __forceinline__ void gld_lds16(const void* g, void* l) {
  as1_u32* gp = (as1_u32*)((uintptr_t)g);
  as3_u32* lp = (as3_u32*)(uint32_t)(uintptr_t)(l);
  __builtin_amdgcn_global_load_lds(gp, lp, 16, 0, 0);
}

// raw v_exp_f32 (2^x), no libm clamp path — inputs bounded here
__device__ __forceinline__ float fast_exp2(float x) {
  float r;
  asm("v_exp_f32 %0, %1" : "=v"(r) : "v"(x));
  return r;
}

// ---------------------------------------------------------------------------
// Kernel 0: f32 -> bf16 convert.
// ---------------------------------------------------------------------------
__global__ __launch_bounds__(256) void f32_to_bf16(
    const float* __restrict__ x, const float* __restrict__ wq,
    const float* __restrict__ wk, const float* __restrict__ wv,
    u16* __restrict__ xc, u16* __restrict__ wqc,
    u16* __restrict__ wkc, u16* __restrict__ wvc) {
  const int z = blockIdx.y;
  const float* src = z == 0 ? x : (z == 1 ? wq : (z == 2 ? wk : wv));
  u16* dst = z == 0 ? xc : (z == 1 ? wqc : (z == 2 ? wkc : wvc));
  const int n = z == 0 ? (1 << 22) : (1 << 20);

  const int idx = (blockIdx.x * 256 + (int)threadIdx.x) * 8;
  if (idx >= n) return;
  const f32x4 a = *(const f32x4*)&src[idx];
  const f32x4 b = *(const f32x4*)&src[idx + 4];
  u16x8 o;
#pragma unroll
  for (int j = 0; j < 4; j++) { o[j] = f2bf(a[j]); o[j + 4] = f2bf(b[j]); }
  *(u16x8*)&dst[idx] = o;
}

// ---------------------------------------------------------------------------
// Kernel 1: QKV GEMM, 128x128 tile, BK=64, XOR-swizzled LDS, plain epilogue.
// Flat grid 768, XCD-aware decode (R7, passing).
// ---------------------------------------------------------------------------
__global__ __launch_bounds__(256) void qkv_gemm(
    const u16* __restrict__ xc, const u16* __restrict__ wqc,
    const u16* __restrict__ wkc, const u16* __restrict__ wvc,
    u16* __restrict__ qo, u16* __restrict__ ko, u16* __restrict__ vt) {
  __shared__ __align__(16) u16 As[128 * 64];
  __shared__ __align__(16) u16 Bs[128 * 64];

  const int tid = threadIdx.x;
  const int lane = tid & 63;
  const int w = tid >> 6;
  const int wm = w >> 1, wn = w & 1;
  const int quad = lane >> 4, m16 = lane & 15;

  const int id    = (int)blockIdx.x;      // 0..767
  const int xcd   = id & 7;
  const int local = id >> 3;              // 0..95
  const int by    = xcd * 4 + (local & 3);
  const int rest  = local >> 2;           // 0..23
  const int which = rest % 3;
  const int bx    = rest / 3;             // 0..7

  const u16* __restrict__ Ap;
  const u16* __restrict__ Bp;
  int m0, n0;
  if (which == 2) {
    Ap = wvc; Bp = xc;
    m0 = bx * 128;   // Wv rows (1024)
    n0 = by * 128;   // x rows (4096)
  } else {
    Ap = xc; Bp = which == 0 ? wqc : wkc;
    m0 = by * 128;   // x rows
    n0 = bx * 128;   // W rows
  }

  const f32x4 z4 = {0.f, 0.f, 0.f, 0.f};
  f32x4 acc[4][4];
#pragma unroll
  for (int i = 0; i < 4; i++)
#pragma unroll
    for (int j = 0; j < 4; j++) acc[i][j] = z4;

  const int lrow = lane >> 3;                       // 0..7
  const int scol = ((lane & 7) ^ (lrow & 7)) * 8;   // pre-swizzled src chunk
  const int srowA = m0 + w * 32 + lrow;
  const int srowB = n0 + w * 32 + lrow;
  const int rsw = m16 & 7;

  for (int k0 = 0; k0 < 1024; k0 += 64) {
    __syncthreads();  // prior MFMA reads of As/Bs complete
#pragma unroll
    for (int j = 0; j < 4; j++) {
      gld_lds16(&Ap[(size_t)(srowA + j * 8) * 1024 + k0 + scol],
                &As[(w * 32 + j * 8) * 64]);
      gld_lds16(&Bp[(size_t)(srowB + j * 8) * 1024 + k0 + scol],
                &Bs[(w * 32 + j * 8) * 64]);
    }
    __syncthreads();  // drains vmcnt -> tiles ready

#pragma unroll
    for (int kk = 0; kk < 2; kk++) {
      bf16x8 af[4], bfr[4];
#pragma unroll
      for (int t = 0; t < 4; t++) {
        af[t] = *(const bf16x8*)
            &As[(wm * 64 + t * 16 + m16) * 64 + (((kk * 4 + quad) ^ rsw) * 8)];
        bfr[t] = *(const bf16x8*)
            &Bs[(wn * 64 + t * 16 + m16) * 64 + (((kk * 4 + quad) ^ rsw) * 8)];
      }
#pragma unroll
      for (int mt = 0; mt < 4; mt++)
#pragma unroll
        for (int nt = 0; nt < 4; nt++)
          acc[mt][nt] = __builtin_amdgcn_mfma_f32_16x16x32_bf16(
              af[mt], bfr[nt], acc[mt][nt], 0, 0, 0);
    }
  }

  if (which < 2) {
    u16* __restrict__ out = which == 0 ? qo : ko;
#pragma unroll
    for (int mt = 0; mt < 4; mt++) {
      const int row = m0 + wm * 64 + mt * 16 + quad * 4;
#pragma unroll
      for (int nt = 0; nt < 4; nt++) {
        const int n = n0 + wn * 64 + nt * 16 + m16;
        f32x4 a = acc[mt][nt];
#pragma unroll
        for (int r = 0; r < 4; r++)
          out[(size_t)(row + r) * 1024 + n] = f2bf(a[r]);
      }
    }
  } else {
    const int m16p = (m16 & 3) | ((m16 & 4) << 1) | ((m16 & 8) >> 1);
#pragma unroll
    for (int mt = 0; mt < 4; mt++) {
      const int row = m0 + wm * 64 + mt * 16 + quad * 4;  // d index
#pragma unroll
      for (int nt = 0; nt < 4; nt++) {
        const int n = n0 + wn * 64 + nt * 16 + m16p;      // x row (permuted)
        f32x4 a = acc[mt][nt];
#pragma unroll
        for (int r = 0; r < 4; r++)
          vt[(size_t)(row + r) * 4096 + n] = f2bf(a[r]);
      }
    }
  }
}

// ---------------------------------------------------------------------------
// Kernel 2: RoPE in-place, standalone (R5 proven): u16x8 + HW trig.
// ---------------------------------------------------------------------------
__global__ __launch_bounds__(256) void rope_inplace(u16* __restrict__ qb,
                                                    u16* __restrict__ kb) {
  u16* buf = blockIdx.y == 0 ? qb : kb;
  const int p = blockIdx.x * 256 + (int)threadIdx.x;
  const int e0 = p * 8;
  const int row = e0 >> 10;
  const int col0 = e0 & 1023;
  const int t = row & 2047;
  const float tf = (float)t;

  u16x8 d = *(const u16x8*)&buf[(size_t)row * 1024 + col0];
  u16x8 o;
#pragma unroll
  for (int j = 0; j < 4; j++) {
    const int i = ((col0 & 63) >> 1) + j;
    const float th = fast_exp2(-(float)i * 0.02595256324130752f);
    const float rev = tf * th * 0.15915494309189535f;
    float fr, s, c;
    asm("v_fract_f32 %0, %1" : "=v"(fr) : "v"(rev));
    asm("v_sin_f32 %0, %1" : "=v"(s) : "v"(fr));
    asm("v_cos_f32 %0, %1" : "=v"(c) : "v"(fr));
    const float a0 = bf2f(d[2 * j]), a1 = bf2f(d[2 * j + 1]);
    o[2 * j]     = f2bf(a0 * c - a1 * s);
    o[2 * j + 1] = f2bf(a1 * c + a0 * s);
  }
  *(u16x8*)&buf[(size_t)row * 1024 + col0] = o;
}

// ---------------------------------------------------------------------------
// Kernel 3: causal flash attention — R7 structure with two latency fixes.
// R10 proved balance was NOT the cost (17 balanced rounds @1 block/CU still
// ~2.6us/round vs ~1500cy pipe work): per-round LATENCY is. Fixes:
// (a) V NEVER STAGED: PV B-frags loaded directly from L2 (vt rows; 4 lanes
//     share each 64B line -> clean gather), issued ~600cy before first use
//     (after softmax-A) so latency hides under softmax-B + l-MFMAs. Kills
//     16KB ds_writes + 64KB redundant ds_reads per block-round (LDS traffic
//     halves; LDS 71.7 -> 36.9KB; barrier now guards K only).
// (b) K-PREFETCH MOVED AFTER THE BARRIER (T14 issue-early/write-late done
//     right): R7 issued prefetch pre-barrier, and __syncthreads' implicit
//     s_waitcnt vmcnt(0) drained the full L2 latency INSIDE the barrier
//     every round. Post-barrier issue -> consumed at next round's staging
//     with a counted wait, hidden under ~2000cy of compute; barrier drain
//     becomes free.
// Else identical to R7/R9: 512 blocks, 32 q-rows/wave, KVBLK=128, dbuf Ks,
// 1 barrier/round, in-reg P (T12), l via ones-MFMA, fast exp2, XCD-local
// decode (id&7 = XCD sees 4 heads).
// ---------------------------------------------------------------------------
__global__ __launch_bounds__(256, 2) void flash_attn(
    const u16* __restrict__ qg, const u16* __restrict__ kg,
    const u16* __restrict__ vt, float* __restrict__ out) {
  __shared__ __align__(16) u16 Ks[2][128 * 72];   // [key][d] (V not staged)

  const int tid = threadIdx.x, lane = tid & 63, w = tid >> 6;
  const int quad = lane >> 4, m16 = lane & 15;

  const int id    = (int)blockIdx.x;  // 0..511
  const int lower = id & 255;
  const int j     = id >> 8;
  const int X     = lower & 7;        // XCD
  const int vloc  = (lower >> 3) & 3;
  const int kk_   = lower >> 5;       // 0..7
  const int Q     = j ? 15 - kk_ : kk_;   // 128-row q-tile index
  const int v     = X * 4 + vloc;     // (b,h) combo
  const int h     = v & 15;
  const int b     = v >> 4;

  const size_t base  = (size_t)b * 2048 * 1024 + (size_t)h * 64;
  const size_t vbase = (size_t)(h * 64) * 4096 + (size_t)b * 2048;
  const float SC = 0.03125f * LOG2E;
  const f32x4 z4 = {0.f, 0.f, 0.f, 0.f};
  const int srow = tid >> 2, sc = (tid & 3) * 16;

  union { u16x8 u; bf16x8 f; } ones;
#pragma unroll
  for (int k = 0; k < 8; k++) ones.u[k] = 0x3F80;  // bf16 1.0

  const int q0 = Q * 128;
  const int nr = Q + 1;  // rounds of 128 keys

  // Q fragments for both subtiles, straight from global (L2-hit).
  const u16* qsA = &qg[base + (size_t)(q0 + w * 32 + m16) * 1024 + quad * 8];
  const bf16x8 qfA0 = *(const bf16x8*)qsA;
  const bf16x8 qfA1 = *(const bf16x8*)(qsA + 32);
  const u16* qsB = qsA + (size_t)16 * 1024;
  const bf16x8 qfB0 = *(const bf16x8*)qsB;
  const bf16x8 qfB1 = *(const bf16x8*)(qsB + 32);

  // Prefetch K round 0 into regs (prologue only; exposed once).
  u16x8 kr0, kr1, kr2, kr3;
  {
    const u16* kp = &kg[base + (size_t)srow * 1024 + sc];
    kr0 = *(const u16x8*)kp; kr1 = *(const u16x8*)(kp + 8);
    const u16* kp2 = kp + (size_t)64 * 1024;
    kr2 = *(const u16x8*)kp2; kr3 = *(const u16x8*)(kp2 + 8);
  }

  f32x4 lA = z4, lB = z4;
  f32x4 OA[4], OB[4];
#pragma unroll
  for (int d = 0; d < 4; d++) { OA[d] = z4; OB[d] = z4; }

  const int qrowA = q0 + w * 32 + quad * 4;  // O store rows (subtile A)
  const int qcolA = q0 + w * 32 + m16;       // softmax q (subtile A)

  int p = 0;
  for (int rr = 0; rr < nr; ++rr) {
    const int k0 = rr * 128;
    // stage K round rr into buf p (counted wait on kr only)
    u16* ksp = &Ks[p][0];
    *(u16x8*)&ksp[srow * 72 + sc] = kr0;
    *(u16x8*)&ksp[srow * 72 + sc + 8] = kr1;
    *(u16x8*)&ksp[(64 + srow) * 72 + sc] = kr2;
    *(u16x8*)&ksp[(64 + srow) * 72 + sc + 8] = kr3;
    __syncthreads();  // vmcnt already drained (prefetch consumed) -> cheap

    // K-prefetch for round rr+1, issued POST-barrier: latency hides under
    // this round's compute; consumed at next round's staging.
    if (rr + 1 < nr) {
      const u16* kp = &kg[base + (size_t)(k0 + 128 + srow) * 1024 + sc];
      kr0 = *(const u16x8*)kp; kr1 = *(const u16x8*)(kp + 8);
      const u16* kp2 = kp + (size_t)64 * 1024;
      kr2 = *(const u16x8*)kp2; kr3 = *(const u16x8*)(kp2 + 8);
    }

    // S^T = K Q^T over 128 keys for BOTH subtiles; K frags read ONCE.
    f32x4 SA[8], SB[8];
#pragma unroll
    for (int nt = 0; nt < 8; nt++) {
      const bf16x8 kf0 = *(const bf16x8*)&ksp[(nt * 16 + m16) * 72 + quad * 8];
      const bf16x8 kf1 =
          *(const bf16x8*)&ksp[(nt * 16 + m16) * 72 + 32 + quad * 8];
      SA[nt] = __builtin_amdgcn_mfma_f32_16x16x32_bf16(kf0, qfA0, z4, 0, 0, 0);
      SA[nt] = __builtin_amdgcn_mfma_f32_16x16x32_bf16(kf1, qfA1, SA[nt], 0, 0, 0);
      SB[nt] = __builtin_amdgcn_mfma_f32_16x16x32_bf16(kf0, qfB0, z4, 0, 0, 0);
      SB[nt] = __builtin_amdgcn_mfma_f32_16x16x32_bf16(kf1, qfB1, SB[nt], 0, 0, 0);
    }

    const bool lastr = (rr == nr - 1);

    union { u32v4 u; bf16x8 f; } PA[4], PB[4];
    {  // subtile A: p = exp2(s*SC), mask last round, pack, assemble frags
      uint32_t W[16];
#pragma unroll
      for (int nt = 0; nt < 8; nt++) {
        float pe[4];
#pragma unroll
        for (int r = 0; r < 4; r++) {
          float e = fast_exp2(SA[nt][r] * SC);
          const int key = k0 + nt * 16 + quad * 4 + r;
          if (lastr && key > qcolA) e = 0.f;
          pe[r] = e;
        }
        uint32_t w0, w1;
        asm("v_cvt_pk_bf16_f32 %0, %1, %2" : "=v"(w0) : "v"(pe[0]), "v"(pe[1]));
        asm("v_cvt_pk_bf16_f32 %0, %1, %2" : "=v"(w1) : "v"(pe[2]), "v"(pe[3]));
        W[2 * nt] = w0; W[2 * nt + 1] = w1;
      }
#pragma unroll
      for (int ks = 0; ks < 4; ks++) {
        uint32_t a0 = W[4 * ks], b0 = W[4 * ks + 2];
        uint32_t a1 = W[4 * ks + 1], b1 = W[4 * ks + 3];
        asm("v_permlane32_swap_b32 %0, %1" : "+v"(a0), "+v"(b0));
        asm("v_permlane32_swap_b32 %0, %1" : "+v"(a1), "+v"(b1));
        PA[ks].u = (u32v4){a0, a1, b0, b1};
      }
    }

    // V fragments DIRECT from L2 for this round — issued here so ~600cy of
    // softmax-B + l-MFMAs cover the load latency before first PV use.
    bf16x8 vf[4][4];
#pragma unroll
    for (int dt = 0; dt < 4; dt++)
#pragma unroll
      for (int ks = 0; ks < 4; ks++)
        vf[dt][ks] = *(const bf16x8*)
            &vt[vbase + (size_t)(dt * 16 + m16) * 4096 + k0 + ks * 32 + quad * 8];

    {  // subtile B
      const int qcolB = qcolA + 16;
      uint32_t W[16];
#pragma unroll
      for (int nt = 0; nt < 8; nt++) {
        float pe[4];
#pragma unroll
        for (int r = 0; r < 4; r++) {
          float e = fast_exp2(SB[nt][r] * SC);
          const int key = k0 + nt * 16 + quad * 4 + r;
          if (lastr && key > qcolB) e = 0.f;
          pe[r] = e;
        }
        uint32_t w0, w1;
        asm("v_cvt_pk_bf16_f32 %0, %1, %2" : "=v"(w0) : "v"(pe[0]), "v"(pe[1]));
        asm("v_cvt_pk_bf16_f32 %0, %1, %2" : "=v"(w1) : "v"(pe[2]), "v"(pe[3]));
        W[2 * nt] = w0; W[2 * nt + 1] = w1;
      }
#pragma unroll
      for (int ks = 0; ks < 4; ks++) {
        uint32_t a0 = W[4 * ks], b0 = W[4 * ks + 2];
        uint32_t a1 = W[4 * ks + 1], b1 = W[4 * ks + 3];
        asm("v_permlane32_swap_b32 %0, %1" : "+v"(a0), "+v"(b0));
        asm("v_permlane32_swap_b32 %0, %1" : "+v"(a1), "+v"(b1));
        PB[ks].u = (u32v4){a0, a1, b0, b1};
      }
    }

    // l += P * ones (row sums of rounded P)
#pragma unroll
    for (int ks = 0; ks < 4; ks++) {
      lA = __builtin_amdgcn_mfma_f32_16x16x32_bf16(PA[ks].f, ones.f, lA, 0, 0, 0);
      lB = __builtin_amdgcn_mfma_f32_16x16x32_bf16(PB[ks].f, ones.f, lB, 0, 0, 0);
    }

    // O += P V (V frags from regs; loads drained by counted vmcnt here)
#pragma unroll
    for (int dt = 0; dt < 4; dt++) {
#pragma unroll
      for (int ks = 0; ks < 4; ks++) {
        OA[dt] = __builtin_amdgcn_mfma_f32_16x16x32_bf16(PA[ks].f, vf[dt][ks],
                                                         OA[dt], 0, 0, 0);
        OB[dt] = __builtin_amdgcn_mfma_f32_16x16x32_bf16(PB[ks].f, vf[dt][ks],
                                                         OB[dt], 0, 0, 0);
      }
    }
    p ^= 1;
  }

  float invA[4], invB[4];
#pragma unroll
  for (int r = 0; r < 4; r++) { invA[r] = 1.0f / lA[r]; invB[r] = 1.0f / lB[r]; }

#pragma unroll
  for (int dt = 0; dt < 4; dt++)
#pragma unroll
    for (int r = 0; r < 4; r++) {
      out[base + (size_t)(qrowA + r) * 1024 + dt * 16 + m16] =
          OA[dt][r] * invA[r];
      out[base + (size_t)(qrowA + 16 + r) * 1024 + dt * 16 + m16] =
          OB[dt][r] * invB[r];
    }
}

extern "C" void kernel_launch(void* const* d_in, const int* in_sizes, int n_in,
                              void* d_out, int out_size, void* d_ws, size_t ws_size,
                              hipStream_t stream) {
  const float* x  = (const float*)d_in[0];
  const float* Wq = (const float*)d_in[1];
  const float* Wk = (const float*)d_in[2];
  const float* Wv = (const float*)d_in[3];
  u16* qb  = (u16*)d_ws;                    // [4096][1024] bf16
  u16* kb  = qb  + (size_t)4096 * 1024;     // [4096][1024] bf16
  u16* vtw = kb  + (size_t)4096 * 1024;     // [1024][4096] bf16 (V^T, swap23)
  u16* xc  = vtw + (size_t)4096 * 1024;     // bf16 inputs
  u16* wqc = xc  + (size_t)4096 * 1024;
  u16* wkc = wqc + (size_t)1024 * 1024;
  u16* wvc = wkc + (size_t)1024 * 1024;

  f32_to_bf16<<<dim3(2048, 4), 256, 0, stream>>>(x, Wq, Wk, Wv,
                                                 xc, wqc, wkc, wvc);
  qkv_gemm<<<dim3(768, 1, 1), 256, 0, stream>>>(xc, wqc, wkc, wvc,
                                                qb, kb, vtw);
  rope_inplace<<<dim3(2048, 2), 256, 0, stream>>>(qb, kb);
  flash_attn<<<dim3(512, 1, 1), 256, 0, stream>>>(qb, kb, vtw, (float*)d_out);
}

// Round 12
// 150.389 us; speedup vs baseline: 1.1510x; 1.1510x over previous
//
#include <hip/hip_runtime.h>
#include <stdint.h>

typedef unsigned short u16;
typedef __bf16 bf16x8 __attribute__((ext_vector_type(8)));
typedef unsigned short u16x8 __attribute__((ext_vector_type(8)));
typedef float f32x4 __attribute__((ext_vector_type(4)));
typedef uint32_t u32v4 __attribute__((ext_vector_type(4)));

#define LOG2E 1.4426950408889634f

typedef const __attribute__((address_space(1))) uint32_t as1_u32;
typedef __attribute__((address_space(3))) uint32_t as3_u32;

// float -> bf16 round-to-nearest-even
__device__ __forceinline__ u16 f2bf(float f) {
  union { float f; uint32_t i; } v; v.f = f;
  uint32_t r = (v.i + 0x7fffu + ((v.i >> 16) & 1u)) >> 16;
  return (u16)r;
}
__device__ __forceinline__ float bf2f(u16 u) {
  union { uint32_t i; float f; } v; v.i = ((uint32_t)u) << 16; return v.f;
}

// async global->LDS, 16B/lane. LDS dest = wave-uniform base; HW scatters
// lane i to base + i*16B.
__device__ __forceinline__ void gld_lds16(const void* g, void* l) {
  as1_u32* gp = (as1_u32*)((uintptr_t)g);
  as3_u32* lp = (as3_u32*)(uint32_t)(uintptr_t)(l);
  __builtin_amdgcn_global_load_lds(gp, lp, 16, 0, 0);
}

// raw v_exp_f32 (2^x), no libm clamp path — inputs bounded here
__device__ __forceinline__ float fast_exp2(float x) {
  float r;
  asm("v_exp_f32 %0, %1" : "=v"(r) : "v"(x));
  return r;
}

// ---------------------------------------------------------------------------
// Kernel 0: f32 -> bf16 convert.
// ---------------------------------------------------------------------------
__global__ __launch_bounds__(256) void f32_to_bf16(
    const float* __restrict__ x, const float* __restrict__ wq,
    const float* __restrict__ wk, const float* __restrict__ wv,
    u16* __restrict__ xc, u16* __restrict__ wqc,
    u16* __restrict__ wkc, u16* __restrict__ wvc) {
  const int z = blockIdx.y;
  const float* src = z == 0 ? x : (z == 1 ? wq : (z == 2 ? wk : wv));
  u16* dst = z == 0 ? xc : (z == 1 ? wqc : (z == 2 ? wkc : wvc));
  const int n = z == 0 ? (1 << 22) : (1 << 20);

  const int idx = (blockIdx.x * 256 + (int)threadIdx.x) * 8;
  if (idx >= n) return;
  const f32x4 a = *(const f32x4*)&src[idx];
  const f32x4 b = *(const f32x4*)&src[idx + 4];
  u16x8 o;
#pragma unroll
  for (int j = 0; j < 4; j++) { o[j] = f2bf(a[j]); o[j + 4] = f2bf(b[j]); }
  *(u16x8*)&dst[idx] = o;
}

// ---------------------------------------------------------------------------
// Kernel 1: QKV GEMM, 128x128 tile, BK=64, XOR-swizzled LDS — now DOUBLE-
// BUFFERED with ONE barrier per K-step (the same T3-minimum fix that took
// flash from 48 to 45.8 in R7). m97-structure's known ~20% stall is the
// vmcnt(0) drain of just-issued global_load_lds DMAs at the barrier; with
// dbuf the DMA for tile t+1 is issued BEFORE compute of tile t, so the
// drain at the end-of-step barrier lands after ~500cy of MFMA+ds_read and
// the (XCD-local, L2-hit) load latency is covered. Hazards: writes(t)->p^1
// after reads(t-1)->p^1 (barrier waits lgkm); reads(t)->p after DMA(t-1)
// (barrier waits vmcnt). LDS 64KB -> 2 blocks/CU.
// Flat grid 768, XCD-aware decode (R7, passing).
//  z=0/1: q/k = x @ W^T -> [4096][1024]
//  z=2  : vt = Wv @ x^T -> [1024][4096], key swap23 folded into store col.
// ---------------------------------------------------------------------------
__global__ __launch_bounds__(256) void qkv_gemm(
    const u16* __restrict__ xc, const u16* __restrict__ wqc,
    const u16* __restrict__ wkc, const u16* __restrict__ wvc,
    u16* __restrict__ qo, u16* __restrict__ ko, u16* __restrict__ vt) {
  __shared__ __align__(16) u16 As[2][128 * 64];
  __shared__ __align__(16) u16 Bs[2][128 * 64];

  const int tid = threadIdx.x;
  const int lane = tid & 63;
  const int w = tid >> 6;
  const int wm = w >> 1, wn = w & 1;
  const int quad = lane >> 4, m16 = lane & 15;

  const int id    = (int)blockIdx.x;      // 0..767
  const int xcd   = id & 7;
  const int local = id >> 3;              // 0..95
  const int by    = xcd * 4 + (local & 3);
  const int rest  = local >> 2;           // 0..23
  const int which = rest % 3;
  const int bx    = rest / 3;             // 0..7

  const u16* __restrict__ Ap;
  const u16* __restrict__ Bp;
  int m0, n0;
  if (which == 2) {
    Ap = wvc; Bp = xc;
    m0 = bx * 128;   // Wv rows (1024)
    n0 = by * 128;   // x rows (4096)
  } else {
    Ap = xc; Bp = which == 0 ? wqc : wkc;
    m0 = by * 128;   // x rows
    n0 = bx * 128;   // W rows
  }

  const f32x4 z4 = {0.f, 0.f, 0.f, 0.f};
  f32x4 acc[4][4];
#pragma unroll
  for (int i = 0; i < 4; i++)
#pragma unroll
    for (int j = 0; j < 4; j++) acc[i][j] = z4;

  // staging: lane i -> row (i>>3), chunk slot (i&7); src chunk = slot^(row&7)
  const int lrow = lane >> 3;                       // 0..7
  const int scol = ((lane & 7) ^ (lrow & 7)) * 8;   // pre-swizzled src chunk
  const int srowA = m0 + w * 32 + lrow;
  const int srowB = n0 + w * 32 + lrow;
  const int rsw = m16 & 7;

  // prologue: stage K-step 0 into buf 0, drain once.
#pragma unroll
  for (int j = 0; j < 4; j++) {
    gld_lds16(&Ap[(size_t)(srowA + j * 8) * 1024 + scol],
              &As[0][(w * 32 + j * 8) * 64]);
    gld_lds16(&Bp[(size_t)(srowB + j * 8) * 1024 + scol],
              &Bs[0][(w * 32 + j * 8) * 64]);
  }
  __syncthreads();  // vmcnt(0): buf0 ready

  int p = 0;
  for (int k0 = 0; k0 < 1024; k0 += 64) {
    // issue DMA for K-step t+1 into buf p^1 (in flight during compute)
    if (k0 + 64 < 1024) {
#pragma unroll
      for (int j = 0; j < 4; j++) {
        gld_lds16(&Ap[(size_t)(srowA + j * 8) * 1024 + k0 + 64 + scol],
                  &As[p ^ 1][(w * 32 + j * 8) * 64]);
        gld_lds16(&Bp[(size_t)(srowB + j * 8) * 1024 + k0 + 64 + scol],
                  &Bs[p ^ 1][(w * 32 + j * 8) * 64]);
      }
    }

    // compute on buf p
#pragma unroll
    for (int kk = 0; kk < 2; kk++) {
      bf16x8 af[4], bfr[4];
#pragma unroll
      for (int t = 0; t < 4; t++) {
        af[t] = *(const bf16x8*)
            &As[p][(wm * 64 + t * 16 + m16) * 64 + (((kk * 4 + quad) ^ rsw) * 8)];
        bfr[t] = *(const bf16x8*)
            &Bs[p][(wn * 64 + t * 16 + m16) * 64 + (((kk * 4 + quad) ^ rsw) * 8)];
      }
#pragma unroll
      for (int mt = 0; mt < 4; mt++)
#pragma unroll
        for (int nt = 0; nt < 4; nt++)
          acc[mt][nt] = __builtin_amdgcn_mfma_f32_16x16x32_bf16(
              af[mt], bfr[nt], acc[mt][nt], 0, 0, 0);
    }
    __syncthreads();  // drains vmcnt (DMA t+1, mostly complete) + lgkm
    p ^= 1;
  }

  if (which < 2) {
    u16* __restrict__ out = which == 0 ? qo : ko;
#pragma unroll
    for (int mt = 0; mt < 4; mt++) {
      const int row = m0 + wm * 64 + mt * 16 + quad * 4;
#pragma unroll
      for (int nt = 0; nt < 4; nt++) {
        const int n = n0 + wn * 64 + nt * 16 + m16;
        f32x4 a = acc[mt][nt];
#pragma unroll
        for (int r = 0; r < 4; r++)
          out[(size_t)(row + r) * 1024 + n] = f2bf(a[r]);
      }
    }
  } else {
    const int m16p = (m16 & 3) | ((m16 & 4) << 1) | ((m16 & 8) >> 1);
#pragma unroll
    for (int mt = 0; mt < 4; mt++) {
      const int row = m0 + wm * 64 + mt * 16 + quad * 4;  // d index
#pragma unroll
      for (int nt = 0; nt < 4; nt++) {
        const int n = n0 + wn * 64 + nt * 16 + m16p;      // x row (permuted)
        f32x4 a = acc[mt][nt];
#pragma unroll
        for (int r = 0; r < 4; r++)
          vt[(size_t)(row + r) * 4096 + n] = f2bf(a[r]);
      }
    }
  }
}

// ---------------------------------------------------------------------------
// Kernel 2: RoPE in-place, standalone (R5 proven): u16x8 + HW trig.
// ---------------------------------------------------------------------------
__global__ __launch_bounds__(256) void rope_inplace(u16* __restrict__ qb,
                                                    u16* __restrict__ kb) {
  u16* buf = blockIdx.y == 0 ? qb : kb;
  const int p = blockIdx.x * 256 + (int)threadIdx.x;
  const int e0 = p * 8;
  const int row = e0 >> 10;
  const int col0 = e0 & 1023;
  const int t = row & 2047;
  const float tf = (float)t;

  u16x8 d = *(const u16x8*)&buf[(size_t)row * 1024 + col0];
  u16x8 o;
#pragma unroll
  for (int j = 0; j < 4; j++) {
    const int i = ((col0 & 63) >> 1) + j;
    const float th = fast_exp2(-(float)i * 0.02595256324130752f);
    const float rev = tf * th * 0.15915494309189535f;
    float fr, s, c;
    asm("v_fract_f32 %0, %1" : "=v"(fr) : "v"(rev));
    asm("v_sin_f32 %0, %1" : "=v"(s) : "v"(fr));
    asm("v_cos_f32 %0, %1" : "=v"(c) : "v"(fr));
    const float a0 = bf2f(d[2 * j]), a1 = bf2f(d[2 * j + 1]);
    o[2 * j]     = f2bf(a0 * c - a1 * s);
    o[2 * j + 1] = f2bf(a1 * c + a0 * s);
  }
  *(u16x8*)&buf[(size_t)row * 1024 + col0] = o;
}

// ---------------------------------------------------------------------------
// Kernel 3: causal flash attention — R9 EXACTLY (best measured: 45.8us).
// R11's V-direct-from-L2 + post-barrier K-prefetch regressed to 61.9us
// (VALUBusy fell to 16%: waves stalled on vmem; LDS staging is what
// amortizes L2 latency 4-ways — twice-confirmed, R4 + R11). Reverted.
// 512 blocks, 32 q-rows/wave, KVBLK=128, dbuf K+V LDS, 1 barrier/round,
// in-reg P (T12), l via ones-MFMA, fast exp2, XCD-local decode.
// ---------------------------------------------------------------------------
__global__ __launch_bounds__(256, 2) void flash_attn(
    const u16* __restrict__ qg, const u16* __restrict__ kg,
    const u16* __restrict__ vt, float* __restrict__ out) {
  __shared__ __align__(16) u16 Ks[2][128 * 72];   // [key][d]
  __shared__ __align__(16) u16 Vs[2][64 * 136];   // [d][kperm] (vt pre-swz)

  const int tid = threadIdx.x, lane = tid & 63, w = tid >> 6;
  const int quad = lane >> 4, m16 = lane & 15;

  const int id    = (int)blockIdx.x;  // 0..511
  const int lower = id & 255;
  const int j     = id >> 8;
  const int X     = lower & 7;        // XCD
  const int vloc  = (lower >> 3) & 3;
  const int kk_   = lower >> 5;       // 0..7
  const int Q     = j ? 15 - kk_ : kk_;   // 128-row q-tile index
  const int v     = X * 4 + vloc;     // (b,h) combo
  const int h     = v & 15;
  const int b     = v >> 4;

  const size_t base  = (size_t)b * 2048 * 1024 + (size_t)h * 64;
  const size_t vbase = (size_t)(h * 64) * 4096 + (size_t)b * 2048;
  const float SC = 0.03125f * LOG2E;
  const f32x4 z4 = {0.f, 0.f, 0.f, 0.f};
  const int srow = tid >> 2, sc = (tid & 3) * 16;

  union { u16x8 u; bf16x8 f; } ones;
#pragma unroll
  for (int k = 0; k < 8; k++) ones.u[k] = 0x3F80;  // bf16 1.0

  const int q0 = Q * 128;
  const int nr = Q + 1;  // rounds of 128 keys

  // Q fragments for both subtiles, straight from global (L2-hit).
  const u16* qsA = &qg[base + (size_t)(q0 + w * 32 + m16) * 1024 + quad * 8];
  const bf16x8 qfA0 = *(const bf16x8*)qsA;
  const bf16x8 qfA1 = *(const bf16x8*)(qsA + 32);
  const u16* qsB = qsA + (size_t)16 * 1024;
  const bf16x8 qfB0 = *(const bf16x8*)qsB;
  const bf16x8 qfB1 = *(const bf16x8*)(qsB + 32);

  // Prefetch round 0 K/V into regs.
  u16x8 kr0, kr1, kr2, kr3, vr0, vr1, vr2, vr3;
  {
    const u16* ks = &kg[base + (size_t)srow * 1024 + sc];
    kr0 = *(const u16x8*)ks; kr1 = *(const u16x8*)(ks + 8);
    const u16* ks2 = ks + (size_t)64 * 1024;
    kr2 = *(const u16x8*)ks2; kr3 = *(const u16x8*)(ks2 + 8);
    const u16* vs = &vt[vbase + (size_t)srow * 4096 + sc];
    vr0 = *(const u16x8*)vs; vr1 = *(const u16x8*)(vs + 8);
    vr2 = *(const u16x8*)(vs + 64); vr3 = *(const u16x8*)(vs + 72);
  }

  f32x4 lA = z4, lB = z4;
  f32x4 OA[4], OB[4];
#pragma unroll
  for (int d = 0; d < 4; d++) { OA[d] = z4; OB[d] = z4; }

  const int qrowA = q0 + w * 32 + quad * 4;  // O store rows (subtile A)
  const int qcolA = q0 + w * 32 + m16;       // softmax q (subtile A)

  int p = 0;
  for (int rr = 0; rr < nr; ++rr) {
    const int k0 = rr * 128;
    // stage round rr into buf p (overlaps other waves' round rr-1 compute)
    u16* ksp = &Ks[p][0];
    u16* vsp = &Vs[p][0];
    *(u16x8*)&ksp[srow * 72 + sc] = kr0;
    *(u16x8*)&ksp[srow * 72 + sc + 8] = kr1;
    *(u16x8*)&ksp[(64 + srow) * 72 + sc] = kr2;
    *(u16x8*)&ksp[(64 + srow) * 72 + sc + 8] = kr3;
    *(u16x8*)&vsp[srow * 136 + sc] = vr0;
    *(u16x8*)&vsp[srow * 136 + sc + 8] = vr1;
    *(u16x8*)&vsp[srow * 136 + 64 + sc] = vr2;
    *(u16x8*)&vsp[srow * 136 + 64 + sc + 8] = vr3;
    if (rr + 1 < nr) {  // prefetch next round; consumed after next barrier
      const u16* ks = &kg[base + (size_t)(k0 + 128 + srow) * 1024 + sc];
      kr0 = *(const u16x8*)ks; kr1 = *(const u16x8*)(ks + 8);
      const u16* ks2 = ks + (size_t)64 * 1024;
      kr2 = *(const u16x8*)ks2; kr3 = *(const u16x8*)(ks2 + 8);
      const u16* vs = &vt[vbase + (size_t)srow * 4096 + k0 + 128 + sc];
      vr0 = *(const u16x8*)vs; vr1 = *(const u16x8*)(vs + 8);
      vr2 = *(const u16x8*)(vs + 64); vr3 = *(const u16x8*)(vs + 72);
    }
    __syncthreads();  // single barrier: buf p staged; prior buf reads done

    // S^T = K Q^T over 128 keys for BOTH subtiles; K frags read ONCE.
    f32x4 SA[8], SB[8];
#pragma unroll
    for (int nt = 0; nt < 8; nt++) {
      const bf16x8 kf0 = *(const bf16x8*)&ksp[(nt * 16 + m16) * 72 + quad * 8];
      const bf16x8 kf1 =
          *(const bf16x8*)&ksp[(nt * 16 + m16) * 72 + 32 + quad * 8];
      SA[nt] = __builtin_amdgcn_mfma_f32_16x16x32_bf16(kf0, qfA0, z4, 0, 0, 0);
      SA[nt] = __builtin_amdgcn_mfma_f32_16x16x32_bf16(kf1, qfA1, SA[nt], 0, 0, 0);
      SB[nt] = __builtin_amdgcn_mfma_f32_16x16x32_bf16(kf0, qfB0, z4, 0, 0, 0);
      SB[nt] = __builtin_amdgcn_mfma_f32_16x16x32_bf16(kf1, qfB1, SB[nt], 0, 0, 0);
    }

    const bool lastr = (rr == nr - 1);

    union { u32v4 u; bf16x8 f; } PA[4], PB[4];
    {  // subtile A: p = exp2(s*SC), mask last round, pack, assemble frags
      uint32_t W[16];
#pragma unroll
      for (int nt = 0; nt < 8; nt++) {
        float pe[4];
#pragma unroll
        for (int r = 0; r < 4; r++) {
          float e = fast_exp2(SA[nt][r] * SC);
          const int key = k0 + nt * 16 + quad * 4 + r;
          if (lastr && key > qcolA) e = 0.f;
          pe[r] = e;
        }
        uint32_t w0, w1;
        asm("v_cvt_pk_bf16_f32 %0, %1, %2" : "=v"(w0) : "v"(pe[0]), "v"(pe[1]));
        asm("v_cvt_pk_bf16_f32 %0, %1, %2" : "=v"(w1) : "v"(pe[2]), "v"(pe[3]));
        W[2 * nt] = w0; W[2 * nt + 1] = w1;
      }
#pragma unroll
      for (int ks = 0; ks < 4; ks++) {
        uint32_t a0 = W[4 * ks], b0 = W[4 * ks + 2];
        uint32_t a1 = W[4 * ks + 1], b1 = W[4 * ks + 3];
        asm("v_permlane32_swap_b32 %0, %1" : "+v"(a0), "+v"(b0));
        asm("v_permlane32_swap_b32 %0, %1" : "+v"(a1), "+v"(b1));
        PA[ks].u = (u32v4){a0, a1, b0, b1};
      }
    }
    {  // subtile B
      const int qcolB = qcolA + 16;
      uint32_t W[16];
#pragma unroll
      for (int nt = 0; nt < 8; nt++) {
        float pe[4];
#pragma unroll
        for (int r = 0; r < 4; r++) {
          float e = fast_exp2(SB[nt][r] * SC);
          const int key = k0 + nt * 16 + quad * 4 + r;
          if (lastr && key > qcolB) e = 0.f;
          pe[r] = e;
        }
        uint32_t w0, w1;
        asm("v_cvt_pk_bf16_f32 %0, %1, %2" : "=v"(w0) : "v"(pe[0]), "v"(pe[1]));
        asm("v_cvt_pk_bf16_f32 %0, %1, %2" : "=v"(w1) : "v"(pe[2]), "v"(pe[3]));
        W[2 * nt] = w0; W[2 * nt + 1] = w1;
      }
#pragma unroll
      for (int ks = 0; ks < 4; ks++) {
        uint32_t a0 = W[4 * ks], b0 = W[4 * ks + 2];
        uint32_t a1 = W[4 * ks + 1], b1 = W[4 * ks + 3];
        asm("v_permlane32_swap_b32 %0, %1" : "+v"(a0), "+v"(b0));
        asm("v_permlane32_swap_b32 %0, %1" : "+v"(a1), "+v"(b1));
        PB[ks].u = (u32v4){a0, a1, b0, b1};
      }
    }

    // l += P * ones (row sums of rounded P)
#pragma unroll
    for (int ks = 0; ks < 4; ks++) {
      lA = __builtin_amdgcn_mfma_f32_16x16x32_bf16(PA[ks].f, ones.f, lA, 0, 0, 0);
      lB = __builtin_amdgcn_mfma_f32_16x16x32_bf16(PB[ks].f, ones.f, lB, 0, 0, 0);
    }

    // O += P V; V frags read ONCE, feed both subtiles.
#pragma unroll
    for (int dt = 0; dt < 4; dt++) {
#pragma unroll
      for (int ks = 0; ks < 4; ks++) {
        const bf16x8 vf =
            *(const bf16x8*)&vsp[(dt * 16 + m16) * 136 + ks * 32 + quad * 8];
        OA[dt] = __builtin_amdgcn_mfma_f32_16x16x32_bf16(PA[ks].f, vf, OA[dt],
                                                         0, 0, 0);
        OB[dt] = __builtin_amdgcn_mfma_f32_16x16x32_bf16(PB[ks].f, vf, OB[dt],
                                                         0, 0, 0);
      }
    }
    p ^= 1;
  }

  float invA[4], invB[4];
#pragma unroll
  for (int r = 0; r < 4; r++) { invA[r] = 1.0f / lA[r]; invB[r] = 1.0f / lB[r]; }

#pragma unroll
  for (int dt = 0; dt < 4; dt++)
#pragma unroll
    for (int r = 0; r < 4; r++) {
      out[base + (size_t)(qrowA + r) * 1024 + dt * 16 + m16] =
          OA[dt][r] * invA[r];
      out[base + (size_t)(qrowA + 16 + r) * 1024 + dt * 16 + m16] =
          OB[dt][r] * invB[r];
    }
}

extern "C" void kernel_launch(void* const* d_in, const int* in_sizes, int n_in,
                              void* d_out, int out_size, void* d_ws, size_t ws_size,
                              hipStream_t stream) {
  const float* x  = (const float*)d_in[0];
  const float* Wq = (const float*)d_in[1];
  const float* Wk = (const float*)d_in[2];
  const float* Wv = (const float*)d_in[3];
  u16* qb  = (u16*)d_ws;                    // [4096][1024] bf16
  u16* kb  = qb  + (size_t)4096 * 1024;     // [4096][1024] bf16
  u16* vtw = kb  + (size_t)4096 * 1024;     // [1024][4096] bf16 (V^T, swap23)
  u16* xc  = vtw + (size_t)4096 * 1024;     // bf16 inputs
  u16* wqc = xc  + (size_t)4096 * 1024;
  u16* wkc = wqc + (size_t)1024 * 1024;
  u16* wvc = wkc + (size_t)1024 * 1024;

  f32_to_bf16<<<dim3(2048, 4), 256, 0, stream>>>(x, Wq, Wk, Wv,
                                                 xc, wqc, wkc, wvc);
  qkv_gemm<<<dim3(768, 1, 1), 256, 0, stream>>>(xc, wqc, wkc, wvc,
                                                qb, kb, vtw);
  rope_inplace<<<dim3(2048, 2), 256, 0, stream>>>(qb, kb);
  flash_attn<<<dim3(512, 1, 1), 256, 0, stream>>>(qb, kb, vtw, (float*)d_out);
}